// Round 3
// baseline (278.536 us; speedup 1.0000x reference)
//
#include <hip/hip_runtime.h>

#define BATCH   32768
#define IN_DIM  256
#define OUT_DIM 256
#define NB      9      // real basis functions
#define NBP     12     // padded to 12 so BK=96 is a multiple of MFMA K=32
#define NKNOT   13
#define DEG     3

#define TM 128
#define TN 128
#define IC 8                 // input dims per K-chunk
#define BK (IC * NBP)        // 96 padded-k per chunk (3 MFMA k-steps)
#define SAS (BK + 8)         // LDS row stride 104 bf16 = 208 B -> 2-way max aliasing (free)
#define THREADS 256
#define CHUNKS (IN_DIM / IC)         // 32
#define BCH (OUT_DIM * BK)           // bf16 elems per chunk slab in ws = 24576
#define WS_NEED ((size_t)CHUNKS * BCH * 2)   // 1,572,864 B

typedef __bf16 bf16x8 __attribute__((ext_vector_type(8)));
typedef float  f32x4  __attribute__((ext_vector_type(4)));

// Cox-de-Boor with compile-time knots — verbatim from the passing kernels.
__device__ __forceinline__ void bspline9(float x, float bv[NB]) {
    const float t[NKNOT] = {-1.f, -1.f, -1.f, -1.f,
                            -2.f/3.f, -1.f/3.f, 0.f, 1.f/3.f, 2.f/3.f,
                            1.f, 1.f, 1.f, 1.f};
    float b[NKNOT - 1];
#pragma unroll
    for (int j = 0; j < NKNOT - 1; ++j)
        b[j] = (x >= t[j] && x < t[j + 1]) ? 1.f : 0.f;
    if (x >= t[NKNOT - 1]) b[8] = 1.f;
#pragma unroll
    for (int d = 1; d <= DEG; ++d) {
#pragma unroll
        for (int j = 0; j < NKNOT - 1 - d; ++j) {
            float d1 = t[j + d] - t[j];
            float d2 = t[j + d + 1] - t[j + 1];
            float w1 = (d1 > 0.f) ? (x - t[j]) * (1.f / d1) : 0.f;
            float w2 = (d2 > 0.f) ? (t[j + d + 1] - x) * (1.f / d2) : 0.f;
            b[j] = w1 * b[j] + w2 * b[j + 1];
        }
    }
#pragma unroll
    for (int r = 0; r < NB; ++r) bv[r] = b[r];
}

// RNE fp32 -> bf16, packed pair into one dword.
__device__ __forceinline__ unsigned packbf2(float a, float b) {
    unsigned ua = __float_as_uint(a);
    unsigned ub = __float_as_uint(b);
    ua += 0x7FFFu + ((ua >> 16) & 1u);
    ub += 0x7FFFu + ((ub >> 16) & 1u);
    return (ua >> 16) | (ub & 0xFFFF0000u);
}

// ---- pre-kernel: coeff fp32 -> bf16 in per-chunk LDS-staging order ----
// ws[chunk][col][ii*12 + r], r<9 real, r>=9 zero.  Runs every kernel_launch
// (d_ws is re-poisoned before every timed call).
__global__ __launch_bounds__(THREADS) void convert_coeff(
        const float* __restrict__ coeff, __bf16* __restrict__ ws)
{
    int p   = blockIdx.x * THREADS + threadIdx.x;   // 65536 = 256 cols x 256 dims
    int col = p >> 8;
    int i   = p & 255;                              // global input dim
    const float* cp = coeff + ((size_t)col * IN_DIM + i) * NB;
    unsigned d0 = packbf2(cp[0], cp[1]);
    unsigned d1 = packbf2(cp[2], cp[3]);
    unsigned d2 = packbf2(cp[4], cp[5]);
    unsigned d3 = packbf2(cp[6], cp[7]);
    unsigned d4 = packbf2(cp[8], 0.f);
    __bf16* dst = ws + (size_t)(i >> 3) * BCH + (size_t)col * BK + (i & 7) * NBP;
    uint2* q = (uint2*)dst;                         // 24 B, 8-aligned
    q[0] = make_uint2(d0, d1);
    q[1] = make_uint2(d2, d3);
    q[2] = make_uint2(d4, 0u);
}

// ---- main kernel: basis -> LDS (bf16), B tile from ws via wide loads ----
__global__ __launch_bounds__(THREADS, 3) void kan_mfma2(
        const float* __restrict__ x,
        const __bf16* __restrict__ wsB,
        const float* __restrict__ bias,
        float* __restrict__ out)
{
    __shared__ __align__(16) __bf16 sA[TM][SAS];
    __shared__ __align__(16) __bf16 sB[TN][SAS];

    const int tid  = threadIdx.x;
    const int m0   = blockIdx.x * TM;
    const int n0   = blockIdx.y * TN;
    const int lane = tid & 63;
    const int wave = tid >> 6;
    const int wm   = (wave & 1) * 64;
    const int wn   = (wave >> 1) * 64;
    const int quad = lane >> 4;
    const int l16  = lane & 15;
    const int bcol = tid >> 1;            // B-staging: col per 2 threads
    const int bko  = (tid & 1) * 48;      // bf16 offset within col

    f32x4 acc[4][4] = {};

    for (int c = 0; c < CHUNKS; ++c) {
        // issue B chunk loads early (no LDS touch; latency hidden by basis eval)
        const uint4* bs = (const uint4*)(wsB + (size_t)c * BCH + (size_t)n0 * BK
                                         + (size_t)tid * 48);
        uint4 breg[6];
#pragma unroll
        for (int j = 0; j < 6; ++j) breg[j] = bs[j];

        __syncthreads();

        // ---- stage A: basis for TM rows x IC dims ----
#pragma unroll
        for (int q = 0; q < (TM * IC) / THREADS; ++q) {   // 4
            int p   = tid + q * THREADS;
            int ii  = p & (IC - 1);
            int row = p >> 3;
            float xv = x[(size_t)(m0 + row) * IN_DIM + c * IC + ii];
            float bv[NB];
            bspline9(xv, bv);
            unsigned d0 = packbf2(bv[0], bv[1]);
            unsigned d1 = packbf2(bv[2], bv[3]);
            unsigned d2 = packbf2(bv[4], bv[5]);
            unsigned d3 = packbf2(bv[6], bv[7]);
            unsigned d4 = packbf2(bv[8], 0.f);
            uint2* dst = (uint2*)&sA[row][ii * NBP];
            dst[0] = make_uint2(d0, d1);
            dst[1] = make_uint2(d2, d3);
            dst[2] = make_uint2(d4, 0u);
        }

        // ---- stage B: 6 x ds_write_b128 from preloaded regs ----
#pragma unroll
        for (int j = 0; j < 6; ++j)
            *(uint4*)&sB[bcol][bko + j * 8] = breg[j];

        __syncthreads();

        // ---- MFMA: 3 k-steps x 16 tiles ----
#pragma unroll
        for (int ks = 0; ks < BK / 32; ++ks) {
            bf16x8 af[4], bg[4];
#pragma unroll
            for (int mt = 0; mt < 4; ++mt)
                af[mt] = *(const bf16x8*)&sA[wm + mt * 16 + l16][ks * 32 + quad * 8];
#pragma unroll
            for (int nt = 0; nt < 4; ++nt)
                bg[nt] = *(const bf16x8*)&sB[wn + nt * 16 + l16][ks * 32 + quad * 8];
#pragma unroll
            for (int mt = 0; mt < 4; ++mt)
#pragma unroll
                for (int nt = 0; nt < 4; ++nt)
                    acc[mt][nt] = __builtin_amdgcn_mfma_f32_16x16x32_bf16(
                        af[mt], bg[nt], acc[mt][nt], 0, 0, 0);
        }
    }

#pragma unroll
    for (int nt = 0; nt < 4; ++nt) {
        int col = n0 + wn + nt * 16 + l16;
        float bs = bias[col];
#pragma unroll
        for (int mt = 0; mt < 4; ++mt) {
            int row = m0 + wm + mt * 16 + quad * 4;
#pragma unroll
            for (int r = 0; r < 4; ++r)
                out[(size_t)(row + r) * OUT_DIM + col] = acc[mt][nt][r] + bs;
        }
    }
}

// ---- fallback (R2 kernel, known-passing) if ws is too small ----
__global__ __launch_bounds__(THREADS, 3) void kan_mfma_fb(
        const float* __restrict__ x,
        const float* __restrict__ coeff,
        const float* __restrict__ bias,
        float* __restrict__ out)
{
    __shared__ __align__(16) __bf16 sA[TM][SAS];
    __shared__ __align__(16) __bf16 sB[TN][SAS];
    const int tid  = threadIdx.x;
    const int m0   = blockIdx.x * TM;
    const int n0   = blockIdx.y * TN;
    const int lane = tid & 63;
    const int wave = tid >> 6;
    const int wm   = (wave & 1) * 64;
    const int wn   = (wave >> 1) * 64;
    const int quad = lane >> 4;
    const int l16  = lane & 15;
    f32x4 acc[4][4] = {};
    for (int i0 = 0; i0 < IN_DIM; i0 += IC) {
        __syncthreads();
#pragma unroll
        for (int q = 0; q < (TM * IC) / THREADS; ++q) {
            int p   = tid + q * THREADS;
            int ii  = p & (IC - 1);
            int row = p >> 3;
            float xv = x[(size_t)(m0 + row) * IN_DIM + i0 + ii];
            float bv[NB];
            bspline9(xv, bv);
            uint2* dst = (uint2*)&sA[row][ii * NBP];
            dst[0] = make_uint2(packbf2(bv[0], bv[1]), packbf2(bv[2], bv[3]));
            dst[1] = make_uint2(packbf2(bv[4], bv[5]), packbf2(bv[6], bv[7]));
            dst[2] = make_uint2(packbf2(bv[8], 0.f), 0u);
        }
#pragma unroll
        for (int q = 0; q < (TN * IC) / THREADS; ++q) {
            int p   = tid + q * THREADS;
            int ii  = p & (IC - 1);
            int col = p >> 3;
            const float* cp = &coeff[(size_t)(n0 + col) * (IN_DIM * NB)
                                     + (size_t)(i0 + ii) * NB];
            uint2* dst = (uint2*)&sB[col][ii * NBP];
            dst[0] = make_uint2(packbf2(cp[0], cp[1]), packbf2(cp[2], cp[3]));
            dst[1] = make_uint2(packbf2(cp[4], cp[5]), packbf2(cp[6], cp[7]));
            dst[2] = make_uint2(packbf2(cp[8], 0.f), 0u);
        }
        __syncthreads();
#pragma unroll
        for (int ks = 0; ks < BK / 32; ++ks) {
            bf16x8 af[4], bg[4];
#pragma unroll
            for (int mt = 0; mt < 4; ++mt)
                af[mt] = *(const bf16x8*)&sA[wm + mt * 16 + l16][ks * 32 + quad * 8];
#pragma unroll
            for (int nt = 0; nt < 4; ++nt)
                bg[nt] = *(const bf16x8*)&sB[wn + nt * 16 + l16][ks * 32 + quad * 8];
#pragma unroll
            for (int mt = 0; mt < 4; ++mt)
#pragma unroll
                for (int nt = 0; nt < 4; ++nt)
                    acc[mt][nt] = __builtin_amdgcn_mfma_f32_16x16x32_bf16(
                        af[mt], bg[nt], acc[mt][nt], 0, 0, 0);
        }
    }
#pragma unroll
    for (int nt = 0; nt < 4; ++nt) {
        int col = n0 + wn + nt * 16 + l16;
        float bs = bias[col];
#pragma unroll
        for (int mt = 0; mt < 4; ++mt) {
            int row = m0 + wm + mt * 16 + quad * 4;
#pragma unroll
            for (int r = 0; r < 4; ++r)
                out[(size_t)(row + r) * OUT_DIM + col] = acc[mt][nt][r] + bs;
        }
    }
}

extern "C" void kernel_launch(void* const* d_in, const int* in_sizes, int n_in,
                              void* d_out, int out_size, void* d_ws, size_t ws_size,
                              hipStream_t stream) {
    const float* x     = (const float*)d_in[0];   // (32768, 256)
    const float* coeff = (const float*)d_in[1];   // (256, 256, 9)
    const float* bias  = (const float*)d_in[2];   // (256,)
    float* out = (float*)d_out;                   // (32768, 256)

    dim3 grid(BATCH / TM, OUT_DIM / TN);          // 256 x 2

    if (ws_size >= WS_NEED) {
        __bf16* ws = (__bf16*)d_ws;
        convert_coeff<<<(OUT_DIM * IN_DIM) / THREADS, THREADS, 0, stream>>>(coeff, ws);
        kan_mfma2<<<grid, dim3(THREADS), 0, stream>>>(x, ws, bias, out);
    } else {
        kan_mfma_fb<<<grid, dim3(THREADS), 0, stream>>>(x, coeff, bias, out);
    }
}

// Round 4
// 186.382 us; speedup vs baseline: 1.4944x; 1.4944x over previous
//
#include <hip/hip_runtime.h>

#define BATCH   32768
#define IN_DIM  256
#define OUT_DIM 256
#define NB      9      // real basis functions
#define NBP     12     // padded to 12 so BK=96 is a multiple of MFMA K=32
#define NKNOT   13
#define DEG     3

#define TM 64
#define TN 256
#define IC 8                 // input dims per K-chunk
#define BK (IC * NBP)        // 96
#define SAS_A 104            // sA row stride (bf16): 208 B, 16-aligned, 2-way banks
#define THREADS 512
#define CHUNKS (IN_DIM / IC) // 32
#define SLAB 25600           // bf16 elems per chunk slab (256 cols x 100 + bumps)
#define WS_NEED ((size_t)CHUNKS * SLAB * 2)   // 1,638,400 B

typedef __bf16 bf16x8 __attribute__((ext_vector_type(8)));
typedef float  f32x4  __attribute__((ext_vector_type(4)));

// col base offset (bf16 units) in the bumped-stride-100 B layout:
// byte addr = 200*col + 8*(col&1)  ->  every col 16-B aligned, banks 2-way max.
__device__ __host__ __forceinline__ int sb_off(int col) {
    return col * 100 + 4 * (col & 1);
}

// Cox-de-Boor with compile-time knots — verbatim from the passing kernels.
__device__ __forceinline__ void bspline9(float x, float bv[NB]) {
    const float t[NKNOT] = {-1.f, -1.f, -1.f, -1.f,
                            -2.f/3.f, -1.f/3.f, 0.f, 1.f/3.f, 2.f/3.f,
                            1.f, 1.f, 1.f, 1.f};
    float b[NKNOT - 1];
#pragma unroll
    for (int j = 0; j < NKNOT - 1; ++j)
        b[j] = (x >= t[j] && x < t[j + 1]) ? 1.f : 0.f;
    if (x >= t[NKNOT - 1]) b[8] = 1.f;
#pragma unroll
    for (int d = 1; d <= DEG; ++d) {
#pragma unroll
        for (int j = 0; j < NKNOT - 1 - d; ++j) {
            float d1 = t[j + d] - t[j];
            float d2 = t[j + d + 1] - t[j + 1];
            float w1 = (d1 > 0.f) ? (x - t[j]) * (1.f / d1) : 0.f;
            float w2 = (d2 > 0.f) ? (t[j + d + 1] - x) * (1.f / d2) : 0.f;
            b[j] = w1 * b[j] + w2 * b[j + 1];
        }
    }
#pragma unroll
    for (int r = 0; r < NB; ++r) bv[r] = b[r];
}

__device__ __forceinline__ unsigned packbf2(float a, float b) {
    unsigned ua = __float_as_uint(a);
    unsigned ub = __float_as_uint(b);
    ua += 0x7FFFu + ((ua >> 16) & 1u);
    ub += 0x7FFFu + ((ub >> 16) & 1u);
    return (ua >> 16) | (ub & 0xFFFF0000u);
}

// ---- pre-kernel: coeff fp32 -> bf16 into the bumped per-chunk layout ----
// ws[chunk][sb_off(col) + ii*12 + r]
__global__ __launch_bounds__(256) void convert_coeff(
        const float* __restrict__ coeff, __bf16* __restrict__ ws)
{
    int p   = blockIdx.x * 256 + threadIdx.x;   // 65536 = 256 cols x 256 dims
    int col = p >> 8;
    int i   = p & 255;
    const float* cp = coeff + ((size_t)col * IN_DIM + i) * NB;
    unsigned d0 = packbf2(cp[0], cp[1]);
    unsigned d1 = packbf2(cp[2], cp[3]);
    unsigned d2 = packbf2(cp[4], cp[5]);
    unsigned d3 = packbf2(cp[6], cp[7]);
    unsigned d4 = packbf2(cp[8], 0.f);
    __bf16* dst = ws + (size_t)(i >> 3) * SLAB + sb_off(col) + (i & 7) * NBP;
    uint2* q = (uint2*)dst;                     // 24 B, 8-aligned
    q[0] = make_uint2(d0, d1);
    q[1] = make_uint2(d2, d3);
    q[2] = make_uint2(d4, 0u);
}

// ---- main: TM=64 x TN=256, 512 thr, 8 waves of 32x64, basis computed once ----
__global__ __launch_bounds__(THREADS, 4) void kan_mfma3(
        const float* __restrict__ x,
        const __bf16* __restrict__ wsB,
        const float* __restrict__ bias,
        float* __restrict__ out)
{
    __shared__ __align__(16) __bf16 sA[TM][SAS_A];   // 13312 B
    __shared__ __align__(16) __bf16 sBf[SLAB];       // 51200 B  (total 64512)

    const int tid  = threadIdx.x;
    const int m0   = blockIdx.x * TM;
    const int lane = tid & 63;
    const int wave = tid >> 6;
    const int wm   = (wave & 1) * 32;     // 2 m-waves x 4 n-waves
    const int wn   = (wave >> 1) * 64;
    const int quad = lane >> 4;
    const int l16  = lane & 15;
    const int arow = tid >> 3;            // basis staging: row 0..63
    const int aii  = tid & 7;
    const int bcol = tid >> 1;            // B staging: col 0..255
    const int bhalf = tid & 1;            // 48 bf16 half

    f32x4 acc[2][4] = {};

    for (int c = 0; c < CHUNKS; ++c) {
        __syncthreads();

        // ---- stage A: one basis eval per thread (64 rows x 8 dims) ----
        {
            float xv = x[(size_t)(m0 + arow) * IN_DIM + c * IC + aii];
            float bv[NB];
            bspline9(xv, bv);
            uint2* dst = (uint2*)&sA[arow][aii * NBP];
            dst[0] = make_uint2(packbf2(bv[0], bv[1]), packbf2(bv[2], bv[3]));
            dst[1] = make_uint2(packbf2(bv[4], bv[5]), packbf2(bv[6], bv[7]));
            dst[2] = make_uint2(packbf2(bv[8], 0.f), 0u);
        }

        // ---- stage B: 96 B per thread, load->write immediately (no long live range) ----
        {
            const uint4* src = (const uint4*)(wsB + (size_t)c * SLAB
                                              + sb_off(bcol) + bhalf * 48);
            uint4* dst = (uint4*)(&sBf[sb_off(bcol) + bhalf * 48]);
            uint4 r0 = src[0], r1 = src[1], r2 = src[2];
            uint4 r3 = src[3], r4 = src[4], r5 = src[5];
            dst[0] = r0; dst[1] = r1; dst[2] = r2;
            dst[3] = r3; dst[4] = r4; dst[5] = r5;
        }

        __syncthreads();

        // ---- MFMA: 3 k-steps, wave tile 32x64 (2x4 of 16x16) ----
#pragma unroll
        for (int ks = 0; ks < BK / 32; ++ks) {
            bf16x8 af[2], bg[4];
#pragma unroll
            for (int mt = 0; mt < 2; ++mt)
                af[mt] = *(const bf16x8*)&sA[wm + mt * 16 + l16][ks * 32 + quad * 8];
#pragma unroll
            for (int nt = 0; nt < 4; ++nt)
                bg[nt] = *(const bf16x8*)&sBf[sb_off(wn + nt * 16 + l16)
                                              + ks * 32 + quad * 8];
#pragma unroll
            for (int mt = 0; mt < 2; ++mt)
#pragma unroll
                for (int nt = 0; nt < 4; ++nt)
                    acc[mt][nt] = __builtin_amdgcn_mfma_f32_16x16x32_bf16(
                        af[mt], bg[nt], acc[mt][nt], 0, 0, 0);
        }
    }

    // ---- epilogue: D row = quad*4+reg, col = l16 ----
#pragma unroll
    for (int nt = 0; nt < 4; ++nt) {
        int col = wn + nt * 16 + l16;
        float bs = bias[col];
#pragma unroll
        for (int mt = 0; mt < 2; ++mt) {
            int row = m0 + wm + mt * 16 + quad * 4;
#pragma unroll
            for (int r = 0; r < 4; ++r)
                out[(size_t)(row + r) * OUT_DIM + col] = acc[mt][nt][r] + bs;
        }
    }
}

// ---- fallback (R2 kernel, known-passing) if ws is too small ----
#define FTM 128
#define FTN 128
#define FSAS (96 + 8)
__global__ __launch_bounds__(256, 3) void kan_mfma_fb(
        const float* __restrict__ x,
        const float* __restrict__ coeff,
        const float* __restrict__ bias,
        float* __restrict__ out)
{
    __shared__ __align__(16) __bf16 sA[FTM][FSAS];
    __shared__ __align__(16) __bf16 sB[FTN][FSAS];
    const int tid  = threadIdx.x;
    const int m0   = blockIdx.x * FTM;
    const int n0   = blockIdx.y * FTN;
    const int lane = tid & 63;
    const int wave = tid >> 6;
    const int wm   = (wave & 1) * 64;
    const int wn   = (wave >> 1) * 64;
    const int quad = lane >> 4;
    const int l16  = lane & 15;
    f32x4 acc[4][4] = {};
    for (int i0 = 0; i0 < IN_DIM; i0 += IC) {
        __syncthreads();
#pragma unroll
        for (int q = 0; q < (FTM * IC) / 256; ++q) {
            int p   = tid + q * 256;
            int ii  = p & (IC - 1);
            int row = p >> 3;
            float xv = x[(size_t)(m0 + row) * IN_DIM + i0 + ii];
            float bv[NB];
            bspline9(xv, bv);
            uint2* dst = (uint2*)&sA[row][ii * NBP];
            dst[0] = make_uint2(packbf2(bv[0], bv[1]), packbf2(bv[2], bv[3]));
            dst[1] = make_uint2(packbf2(bv[4], bv[5]), packbf2(bv[6], bv[7]));
            dst[2] = make_uint2(packbf2(bv[8], 0.f), 0u);
        }
#pragma unroll
        for (int q = 0; q < (FTN * IC) / 256; ++q) {
            int p   = tid + q * 256;
            int ii  = p & (IC - 1);
            int col = p >> 3;
            const float* cp = &coeff[(size_t)(n0 + col) * (IN_DIM * NB)
                                     + (size_t)(i0 + ii) * NB];
            uint2* dst = (uint2*)&sB[col][ii * NBP];
            dst[0] = make_uint2(packbf2(cp[0], cp[1]), packbf2(cp[2], cp[3]));
            dst[1] = make_uint2(packbf2(cp[4], cp[5]), packbf2(cp[6], cp[7]));
            dst[2] = make_uint2(packbf2(cp[8], 0.f), 0u);
        }
        __syncthreads();
#pragma unroll
        for (int ks = 0; ks < BK / 32; ++ks) {
            bf16x8 af[4], bg[4];
#pragma unroll
            for (int mt = 0; mt < 4; ++mt)
                af[mt] = *(const bf16x8*)&sA[wm + mt * 16 + l16][ks * 32 + quad * 8];
#pragma unroll
            for (int nt = 0; nt < 4; ++nt)
                bg[nt] = *(const bf16x8*)&sB[wn + nt * 16 + l16][ks * 32 + quad * 8];
#pragma unroll
            for (int mt = 0; mt < 4; ++mt)
#pragma unroll
                for (int nt = 0; nt < 4; ++nt)
                    acc[mt][nt] = __builtin_amdgcn_mfma_f32_16x16x32_bf16(
                        af[mt], bg[nt], acc[mt][nt], 0, 0, 0);
        }
    }
#pragma unroll
    for (int nt = 0; nt < 4; ++nt) {
        int col = n0 + wn + nt * 16 + l16;
        float bs = bias[col];
#pragma unroll
        for (int mt = 0; mt < 4; ++mt) {
            int row = m0 + wm + mt * 16 + quad * 4;
#pragma unroll
            for (int r = 0; r < 4; ++r)
                out[(size_t)(row + r) * OUT_DIM + col] = acc[mt][nt][r] + bs;
        }
    }
}

extern "C" void kernel_launch(void* const* d_in, const int* in_sizes, int n_in,
                              void* d_out, int out_size, void* d_ws, size_t ws_size,
                              hipStream_t stream) {
    const float* x     = (const float*)d_in[0];   // (32768, 256)
    const float* coeff = (const float*)d_in[1];   // (256, 256, 9)
    const float* bias  = (const float*)d_in[2];   // (256,)
    float* out = (float*)d_out;                   // (32768, 256)

    if (ws_size >= WS_NEED) {
        __bf16* ws = (__bf16*)d_ws;
        convert_coeff<<<(OUT_DIM * IN_DIM) / 256, 256, 0, stream>>>(coeff, ws);
        kan_mfma3<<<dim3(BATCH / TM, 1), dim3(THREADS), 0, stream>>>(x, ws, bias, out);
    } else {
        dim3 grid(BATCH / FTM, OUT_DIM / FTN);
        kan_mfma_fb<<<grid, dim3(256), 0, stream>>>(x, coeff, bias, out);
    }
}

// Round 5
// 163.042 us; speedup vs baseline: 1.7084x; 1.1432x over previous
//
#include <hip/hip_runtime.h>

#define BATCH   32768
#define IN_DIM  256
#define OUT_DIM 256
#define NB      9      // real basis functions
#define NBP     12     // padded to 12 so BK=96 is a multiple of MFMA K=32
#define NKNOT   13
#define DEG     3

#define TM 64
#define TN 256
#define IC 8                 // input dims per K-chunk
#define BK (IC * NBP)        // 96 padded-k per chunk (3 MFMA k-steps)
#define SAS_A 104            // sA row stride: 208 B, 16-aligned, 2-way banks (verified shape)
#define THREADS 256
#define CHUNKS (IN_DIM / IC)         // 32
#define SLAB (OUT_DIM * BK)          // dense bf16 elems per chunk slab in ws = 24576
#define WS_NEED ((size_t)CHUNKS * SLAB * 2)   // 1,572,864 B

typedef __bf16 bf16x8 __attribute__((ext_vector_type(8)));
typedef float  f32x4  __attribute__((ext_vector_type(4)));

// Cox-de-Boor with compile-time knots — verbatim from the passing kernels.
__device__ __forceinline__ void bspline9(float x, float bv[NB]) {
    const float t[NKNOT] = {-1.f, -1.f, -1.f, -1.f,
                            -2.f/3.f, -1.f/3.f, 0.f, 1.f/3.f, 2.f/3.f,
                            1.f, 1.f, 1.f, 1.f};
    float b[NKNOT - 1];
#pragma unroll
    for (int j = 0; j < NKNOT - 1; ++j)
        b[j] = (x >= t[j] && x < t[j + 1]) ? 1.f : 0.f;
    if (x >= t[NKNOT - 1]) b[8] = 1.f;
#pragma unroll
    for (int d = 1; d <= DEG; ++d) {
#pragma unroll
        for (int j = 0; j < NKNOT - 1 - d; ++j) {
            float d1 = t[j + d] - t[j];
            float d2 = t[j + d + 1] - t[j + 1];
            float w1 = (d1 > 0.f) ? (x - t[j]) * (1.f / d1) : 0.f;
            float w2 = (d2 > 0.f) ? (t[j + d + 1] - x) * (1.f / d2) : 0.f;
            b[j] = w1 * b[j] + w2 * b[j + 1];
        }
    }
#pragma unroll
    for (int r = 0; r < NB; ++r) bv[r] = b[r];
}

__device__ __forceinline__ unsigned packbf2(float a, float b) {
    unsigned ua = __float_as_uint(a);
    unsigned ub = __float_as_uint(b);
    ua += 0x7FFFu + ((ua >> 16) & 1u);
    ub += 0x7FFFu + ((ub >> 16) & 1u);
    return (ua >> 16) | (ub & 0xFFFF0000u);
}

// ---- pre-kernel: coeff fp32 -> bf16, dense per-chunk k-major layout ----
// ws[chunk][col][ii*12 + r]  (192 B per col per chunk, contiguous)
__global__ __launch_bounds__(256) void convert_coeff(
        const float* __restrict__ coeff, __bf16* __restrict__ ws)
{
    int p   = blockIdx.x * 256 + threadIdx.x;   // 65536 = 256 cols x 256 dims
    int col = p >> 8;
    int i   = p & 255;
    const float* cp = coeff + ((size_t)col * IN_DIM + i) * NB;
    unsigned d0 = packbf2(cp[0], cp[1]);
    unsigned d1 = packbf2(cp[2], cp[3]);
    unsigned d2 = packbf2(cp[4], cp[5]);
    unsigned d3 = packbf2(cp[6], cp[7]);
    unsigned d4 = packbf2(cp[8], 0.f);
    __bf16* dst = ws + (size_t)(i >> 3) * SLAB + (size_t)col * BK + (i & 7) * NBP;
    uint2* q = (uint2*)dst;                     // 24 B, 8-aligned
    q[0] = make_uint2(d0, d1);
    q[1] = make_uint2(d2, d3);
    q[2] = make_uint2(d4, 0u);
}

// ---- main: TM=64 x TN=256, 256 thr, 4 waves of 64x64 (4x4 acc).
//      A (basis) through LDS (4x reuse); B fragments straight from L2-resident ws
//      (zero intra-block reuse -> LDS round-trip was pure overhead).
__global__ __launch_bounds__(THREADS, 3) void kan_mfma4(
        const float* __restrict__ x,
        const __bf16* __restrict__ wsB,
        const float* __restrict__ bias,
        float* __restrict__ out)
{
    __shared__ __align__(16) __bf16 sA[TM][SAS_A];   // 13312 B only

    const int tid  = threadIdx.x;
    const int m0   = blockIdx.x * TM;
    const int lane = tid & 63;
    const int wave = tid >> 6;
    const int wn   = wave * 64;           // 4 waves tile the 256-wide N
    const int quad = lane >> 4;
    const int l16  = lane & 15;
    const int arow = tid >> 3;            // basis staging: rows arow, arow+32
    const int aii  = tid & 7;

    f32x4 acc[4][4] = {};   // [mt][nt]

    // B fragment base for this lane: col = wn + l16 (+nt*16), k-offset quad*8
    const __bf16* wb = wsB + (size_t)(wn + l16) * BK + quad * 8;

    for (int c = 0; c < CHUNKS; ++c) {
        __syncthreads();   // previous iteration's sA reads complete

        // ---- stage A: 2 basis evals per thread (rows arow, arow+32) ----
#pragma unroll
        for (int h = 0; h < 2; ++h) {
            int row = arow + h * 32;
            float xv = x[(size_t)(m0 + row) * IN_DIM + c * IC + aii];
            float bv[NB];
            bspline9(xv, bv);
            uint2* dst = (uint2*)&sA[row][aii * NBP];
            dst[0] = make_uint2(packbf2(bv[0], bv[1]), packbf2(bv[2], bv[3]));
            dst[1] = make_uint2(packbf2(bv[4], bv[5]), packbf2(bv[6], bv[7]));
            dst[2] = make_uint2(packbf2(bv[8], 0.f), 0u);
        }

        // ---- B fragments for this chunk: 12 x global b128 from L2-resident ws.
        //      Issued after basis eval (short live range — R3 spill lesson);
        //      latency absorbed by the barrier drain + other waves.
        uint4 breg[3][4];
        {
            const __bf16* wc = wb + (size_t)c * SLAB;
#pragma unroll
            for (int ks = 0; ks < 3; ++ks)
#pragma unroll
                for (int nt = 0; nt < 4; ++nt)
                    breg[ks][nt] = *(const uint4*)(wc + (size_t)nt * 16 * BK + ks * 32);
        }

        __syncthreads();   // sA published

        // ---- MFMA: 3 k-steps x 16 tiles (4x4), A from LDS, B from regs ----
#pragma unroll
        for (int ks = 0; ks < 3; ++ks) {
            bf16x8 af[4];
#pragma unroll
            for (int mt = 0; mt < 4; ++mt)
                af[mt] = *(const bf16x8*)&sA[mt * 16 + l16][ks * 32 + quad * 8];
#pragma unroll
            for (int mt = 0; mt < 4; ++mt)
#pragma unroll
                for (int nt = 0; nt < 4; ++nt)
                    acc[mt][nt] = __builtin_amdgcn_mfma_f32_16x16x32_bf16(
                        af[mt], *(const bf16x8*)&breg[ks][nt], acc[mt][nt], 0, 0, 0);
        }
    }

    // ---- epilogue: D row = quad*4+reg, col = l16 ----
#pragma unroll
    for (int nt = 0; nt < 4; ++nt) {
        int col = wn + nt * 16 + l16;
        float bs = bias[col];
#pragma unroll
        for (int mt = 0; mt < 4; ++mt) {
            int row = m0 + mt * 16 + quad * 4;
#pragma unroll
            for (int r = 0; r < 4; ++r)
                out[(size_t)(row + r) * OUT_DIM + col] = acc[mt][nt][r] + bs;
        }
    }
}

// ---- fallback (known-passing R2 kernel) if ws is too small ----
#define FTM 128
#define FTN 128
#define FSAS (96 + 8)
__global__ __launch_bounds__(256, 3) void kan_mfma_fb(
        const float* __restrict__ x,
        const float* __restrict__ coeff,
        const float* __restrict__ bias,
        float* __restrict__ out)
{
    __shared__ __align__(16) __bf16 sA[FTM][FSAS];
    __shared__ __align__(16) __bf16 sB[FTN][FSAS];
    const int tid  = threadIdx.x;
    const int m0   = blockIdx.x * FTM;
    const int n0   = blockIdx.y * FTN;
    const int lane = tid & 63;
    const int wave = tid >> 6;
    const int wm   = (wave & 1) * 64;
    const int wn   = (wave >> 1) * 64;
    const int quad = lane >> 4;
    const int l16  = lane & 15;
    f32x4 acc[4][4] = {};
    for (int i0 = 0; i0 < IN_DIM; i0 += IC) {
        __syncthreads();
#pragma unroll
        for (int q = 0; q < (FTM * IC) / 256; ++q) {
            int p   = tid + q * 256;
            int ii  = p & (IC - 1);
            int row = p >> 3;
            float xv = x[(size_t)(m0 + row) * IN_DIM + i0 + ii];
            float bv[NB];
            bspline9(xv, bv);
            uint2* dst = (uint2*)&sA[row][ii * NBP];
            dst[0] = make_uint2(packbf2(bv[0], bv[1]), packbf2(bv[2], bv[3]));
            dst[1] = make_uint2(packbf2(bv[4], bv[5]), packbf2(bv[6], bv[7]));
            dst[2] = make_uint2(packbf2(bv[8], 0.f), 0u);
        }
#pragma unroll
        for (int q = 0; q < (FTN * IC) / 256; ++q) {
            int p   = tid + q * 256;
            int ii  = p & (IC - 1);
            int col = p >> 3;
            const float* cp = &coeff[(size_t)(n0 + col) * (IN_DIM * NB)
                                     + (size_t)(i0 + ii) * NB];
            uint2* dst = (uint2*)&sB[col][ii * NBP];
            dst[0] = make_uint2(packbf2(cp[0], cp[1]), packbf2(cp[2], cp[3]));
            dst[1] = make_uint2(packbf2(cp[4], cp[5]), packbf2(cp[6], cp[7]));
            dst[2] = make_uint2(packbf2(cp[8], 0.f), 0u);
        }
        __syncthreads();
#pragma unroll
        for (int ks = 0; ks < BK / 32; ++ks) {
            bf16x8 af[4], bg[4];
#pragma unroll
            for (int mt = 0; mt < 4; ++mt)
                af[mt] = *(const bf16x8*)&sA[wm + mt * 16 + l16][ks * 32 + quad * 8];
#pragma unroll
            for (int nt = 0; nt < 4; ++nt)
                bg[nt] = *(const bf16x8*)&sB[wn + nt * 16 + l16][ks * 32 + quad * 8];
#pragma unroll
            for (int mt = 0; mt < 4; ++mt)
#pragma unroll
                for (int nt = 0; nt < 4; ++nt)
                    acc[mt][nt] = __builtin_amdgcn_mfma_f32_16x16x32_bf16(
                        af[mt], bg[nt], acc[mt][nt], 0, 0, 0);
        }
    }
#pragma unroll
    for (int nt = 0; nt < 4; ++nt) {
        int col = n0 + wn + nt * 16 + l16;
        float bs = bias[col];
#pragma unroll
        for (int mt = 0; mt < 4; ++mt) {
            int row = m0 + wm + mt * 16 + quad * 4;
#pragma unroll
            for (int r = 0; r < 4; ++r)
                out[(size_t)(row + r) * OUT_DIM + col] = acc[mt][nt][r] + bs;
        }
    }
}

extern "C" void kernel_launch(void* const* d_in, const int* in_sizes, int n_in,
                              void* d_out, int out_size, void* d_ws, size_t ws_size,
                              hipStream_t stream) {
    const float* x     = (const float*)d_in[0];   // (32768, 256)
    const float* coeff = (const float*)d_in[1];   // (256, 256, 9)
    const float* bias  = (const float*)d_in[2];   // (256,)
    float* out = (float*)d_out;                   // (32768, 256)

    if (ws_size >= WS_NEED) {
        __bf16* ws = (__bf16*)d_ws;
        convert_coeff<<<(OUT_DIM * IN_DIM) / 256, 256, 0, stream>>>(coeff, ws);
        kan_mfma4<<<dim3(BATCH / TM), dim3(THREADS), 0, stream>>>(x, ws, bias, out);
    } else {
        dim3 grid(BATCH / FTM, OUT_DIM / FTN);
        kan_mfma_fb<<<grid, dim3(256), 0, stream>>>(x, coeff, bias, out);
    }
}